// Round 11
// baseline (121.598 us; speedup 1.0000x reference)
//
#include <hip/hip_runtime.h>

#define HH 1024
#define WW 1024
#define KK 9
#define PADK 4
#define TS 16
#define TILE 24  // TS + 2*PADK
#define KC 9     // chunk = one kernel row (9 weights/pixel)

#define GLDS4(src, dst)                                                \
  __builtin_amdgcn_global_load_lds(                                    \
      (const __attribute__((address_space(1))) unsigned int*)(src),    \
      (__attribute__((address_space(3))) unsigned int*)(dst), 4, 0, 0)

// R2's high-occupancy structure (256 thr, 16x16 px, LDS tile + DMA-staged
// weights) with the barrier-drain fixed: raw s_barrier + counted vmcnt(9)
// + double-buffered KC=9 chunks. The next chunk's DMA stays in flight
// across the current chunk's compute (never vmcnt(0) in the loop), and
// 28 KB LDS -> 5 blocks/CU = 20 waves/CU for cross-block coverage.
// Empirical lesson R5/R10: occupancy dominates; keep it AND pipeline.
__global__ __launch_bounds__(256) void denoiser_kpn(
    const float* __restrict__ unet, const float* __restrict__ cnn,
    float* __restrict__ out) {
  __shared__ float4 tile[TILE][TILE + 1];  // 9600 B, +1 pad
  __shared__ float wlds[2][256 * KC];      // 2 x 9216 B; total 28032 B

  const int tid = threadIdx.x;
  const int tx = tid & 15;
  const int ty = tid >> 4;
  const int bx = blockIdx.x;
  const int by = blockIdx.y;

  // Weight DMA for chunk c (kernel row c) into buffer b: 9 wave-ops, each
  // lane-linear in LDS (uniform base + lane*4); global src spans ~7 pixels
  // x 36 B segments (stride 324) -> ~8 cache lines/instr, L2 re-hits the
  // straddled lines on later chunks. HBM bytes stay at the 340 MB floor.
  auto wdma = [&](int c, int b) {
#pragma unroll
    for (int i = 0; i < KC; ++i) {
      const int g = tid + 256 * i;
      const int p = g / KC;       // pixel in block [0,256)
      const int dk = g - p * KC;  // weight within row-chunk
      const float* src = cnn +
          ((size_t)((by * TS + (p >> 4)) * WW + bx * TS + (p & 15))) * 81 +
          c * KC + dk;
      GLDS4(src, &wlds[b][g]);
    }
  };

  // Prologue: stage 24x24 reflect-padded tile (compiler-managed waits).
  {
    const int y0 = by * TS - PADK, x0 = bx * TS - PADK;
    for (int idx = tid; idx < TILE * TILE; idx += 256) {
      const int i = idx / TILE;
      const int j = idx - i * TILE;
      int gy = y0 + i;
      gy = gy < 0 ? -gy : (gy >= HH ? 2 * HH - 2 - gy : gy);
      int gx = x0 + j;
      gx = gx < 0 ? -gx : (gx >= WW ? 2 * WW - 2 - gx : gx);
      const float* p = unet + ((size_t)gy * WW + gx) * 3;
      tile[i][j] = make_float4(p[0], p[1], p[2], 0.0f);
    }
  }
  __builtin_amdgcn_sched_barrier(0);
  wdma(0, 0);
  wdma(1, 1);
  __builtin_amdgcn_sched_barrier(0);
  // Drain DMA(0) (9 newest = DMA(1) stay in flight); tile ds_writes visible.
  asm volatile("s_waitcnt vmcnt(9) lgkmcnt(0)" ::: "memory");
  __builtin_amdgcn_sched_barrier(0);
  __builtin_amdgcn_s_barrier();  // publish tile + chunk 0
  __builtin_amdgcn_sched_barrier(0);

  float ax = 0.0f, ay = 0.0f, az = 0.0f;

#pragma unroll 1
  for (int c = 0; c < KK; ++c) {
    const int b = c & 1;
    const float* wrow = &wlds[b][tid * KC];
    const float4* trow = &tile[ty + c][tx];
#pragma unroll
    for (int j = 0; j < KC; ++j) {  // 9 taps of kernel row c
      const float4 pv = trow[j];
      const float w = wrow[j];
      ax = fmaf(w, pv.x, ax);
      ay = fmaf(w, pv.y, ay);
      az = fmaf(w, pv.z, az);
    }
    if (c < KK - 1) {
      __builtin_amdgcn_sched_barrier(0);
      __builtin_amdgcn_s_barrier();  // all waves done reading buf b
      __builtin_amdgcn_sched_barrier(0);
      if (c + 2 < KK) {
        wdma(c + 2, b);  // overwrite freed buffer
        __builtin_amdgcn_sched_barrier(0);
        // Drain DMA(c+1); DMA(c+2) (newest 9) rides across next compute.
        asm volatile("s_waitcnt vmcnt(9)" ::: "memory");
      } else {
        asm volatile("s_waitcnt vmcnt(0)" ::: "memory");  // last fill
      }
      __builtin_amdgcn_sched_barrier(0);
      __builtin_amdgcn_s_barrier();  // publish chunk c+1
      __builtin_amdgcn_sched_barrier(0);
    }
  }

  const float o[3] = {ax, ay, az};
  __builtin_memcpy(out + ((size_t)(by * TS + ty) * WW + bx * TS + tx) * 3,
                   &o[0], 12);
}

extern "C" void kernel_launch(void* const* d_in, const int* in_sizes, int n_in,
                              void* d_out, int out_size, void* d_ws, size_t ws_size,
                              hipStream_t stream) {
  const float* unet = (const float*)d_in[0];  // [1024,1024,3] f32
  const float* cnn = (const float*)d_in[1];   // [1024,1024,81] f32
  float* out = (float*)d_out;                 // [1024,1024,3] f32
  dim3 grid(WW / TS, HH / TS);                // 64 x 64 blocks
  dim3 block(256);
  denoiser_kpn<<<grid, block, 0, stream>>>(unet, cnn, out);
}

// Round 12
// 71.304 us; speedup vs baseline: 1.7053x; 1.7053x over previous
//
#include <hip/hip_runtime.h>

#define HH 1024
#define WW 1024
#define KK 9
#define PADK 4
#define TSX 16
#define TSY 8
#define NPX 128    // pixels per block
#define TROWS 16   // TSY + 2*PADK
#define TCOLS 24   // TSX + 2*PADK
#define NW 81
#define ROWB 5184  // 16 px * 324 B, contiguous per image row

#define GLDS(src, dst, w)                                              \
  __builtin_amdgcn_global_load_lds(                                    \
      (const __attribute__((address_space(1))) unsigned int*)(src),    \
      (__attribute__((address_space(3))) unsigned int*)(dst), w, 0, 0)

// Single-pass KPN: 128-thread block = 16x8 pixels. ALL weights staged once
// (no k-chunking -> no multi-pass cache-line re-fetch, the measured R2/R11
// over-fetch). Per image row 5184 contiguous bytes: 5x width-16 DMA + 16-lane
// width-4 tail; wave w stages exactly the rows it consumes (ty in [4w,4w+4)),
// so weight-wait is per-wave vmcnt(0), no cross-wave weight barrier. Tile is
// published with lgkmcnt(0) + raw s_barrier (weight DMA stays in flight).
// LDS 46.75 KB -> 3 blocks/CU: >=2 blocks mid-transfer per CU at all times.
__global__ __launch_bounds__(128) void denoiser_kpn(
    const float* __restrict__ unet, const float* __restrict__ cnn,
    float* __restrict__ out) {
  __shared__ __attribute__((aligned(16))) float wlds[NPX * NW];  // 41472 B
  __shared__ float4 tile[TROWS][TCOLS + 1];                      // 6400 B

  const int tid = threadIdx.x;   // 0..127
  const int lane = tid & 63;
  const int wv = tid >> 6;       // wave 0/1
  const int tx = tid & 15;
  const int ty = tid >> 4;       // 0..7
  const int px0 = blockIdx.x * TSX;
  const int py0 = blockIdx.y * TSY;

  // ---- 1. Tile global loads first (into VGPRs): 384 entries / 128 thr. ----
  float tr_[3][3];
#pragma unroll
  for (int i = 0; i < 3; ++i) {
    const int idx = tid + 128 * i;        // 0..383
    const int r = idx / TCOLS;
    const int c = idx - r * TCOLS;
    int gy = py0 - PADK + r;
    gy = gy < 0 ? -gy : (gy >= HH ? 2 * HH - 2 - gy : gy);
    int gx = px0 - PADK + c;
    gx = gx < 0 ? -gx : (gx >= WW ? 2 * WW - 2 - gx : gx);
    __builtin_memcpy(&tr_[i][0], unet + ((size_t)gy * WW + gx) * 3, 12);
  }
  __builtin_amdgcn_sched_barrier(0);

  // ---- 2. Weight DMA: wave wv stages image rows 4wv..4wv+3 (its own ty
  //         range). Row = 5184 B contiguous: 5 x 1024 B + 64 B tail. ----
#pragma unroll
  for (int rr = 0; rr < 4; ++rr) {
    const int r = wv * 4 + rr;
    const char* s = (const char*)(cnn + ((size_t)(py0 + r) * WW + px0) * NW);
    char* d = (char*)wlds + r * ROWB;
#pragma unroll
    for (int i = 0; i < 5; ++i)
      GLDS(s + i * 1024 + lane * 16, d + i * 1024 + lane * 16, 16);
    if (lane < 16) GLDS(s + 5120 + lane * 4, d + 5120 + lane * 4, 4);
  }
  __builtin_amdgcn_sched_barrier(0);

  // ---- 3. Tile -> LDS (compiler waits the tile loads; weight DMA rides). --
#pragma unroll
  for (int i = 0; i < 3; ++i) {
    const int idx = tid + 128 * i;
    const int r = idx / TCOLS;
    const int c = idx - r * TCOLS;
    tile[r][c] = make_float4(tr_[i][0], tr_[i][1], tr_[i][2], 0.0f);
  }
  __builtin_amdgcn_sched_barrier(0);
  asm volatile("s_waitcnt lgkmcnt(0)" ::: "memory");
  __builtin_amdgcn_s_barrier();  // publish tile; weight DMA still in flight
  __builtin_amdgcn_sched_barrier(0);
  asm volatile("s_waitcnt vmcnt(0)" ::: "memory");  // own rows' weights landed
  __builtin_amdgcn_sched_barrier(0);

  // ---- 4. 81 taps. Weight reads: lane stride 81 dwords -> 2/bank = free.
  //         Tile b128: (ty+tx) mod 8 -> exactly 8 lanes/bank-group = free. --
  float ax = 0.0f, ay = 0.0f, az = 0.0f;
  const float* wrow = wlds + tid * NW;
#pragma unroll
  for (int ki = 0; ki < KK; ++ki)
#pragma unroll
    for (int kj = 0; kj < KK; ++kj) {
      const float4 pv = tile[ty + ki][tx + kj];
      const float w = wrow[ki * KK + kj];
      ax = fmaf(w, pv.x, ax);
      ay = fmaf(w, pv.y, ay);
      az = fmaf(w, pv.z, az);
    }

  const float o[3] = {ax, ay, az};
  __builtin_memcpy(out + ((size_t)(py0 + ty) * WW + px0 + tx) * 3, &o[0], 12);
}

extern "C" void kernel_launch(void* const* d_in, const int* in_sizes, int n_in,
                              void* d_out, int out_size, void* d_ws, size_t ws_size,
                              hipStream_t stream) {
  const float* unet = (const float*)d_in[0];  // [1024,1024,3] f32
  const float* cnn = (const float*)d_in[1];   // [1024,1024,81] f32
  float* out = (float*)d_out;                 // [1024,1024,3] f32
  dim3 grid(WW / TSX, HH / TSY);              // 64 x 128 blocks
  dim3 block(NPX);
  denoiser_kpn<<<grid, block, 0, stream>>>(unet, cnn, out);
}